// Round 4
// baseline (1485.734 us; speedup 1.0000x reference)
//
#include <hip/hip_runtime.h>

#define BB 512   // batch
#define TT 512   // time
#define FF 64    // layer-1 input width
#define HH 128   // hidden
#define G4 512   // 4*H gates
#define NCLS 10
#define WT 4     // staged window (steps)
#define CH 16    // pipeline chunk (steps) for producer->consumer flags
#define XWP1 (FF + 8)    // padded LDS row for layer-1 x (72)
#define XWP2 (HH + 8)    // padded LDS row for layer-2 input (136)
#define HBP  (HH + 8)    // padded LDS row for h (136)
#define ABP  (G4 + 4)    // padded LDS row for raw gates (516)

typedef __attribute__((ext_vector_type(8))) short short8;
typedef __attribute__((ext_vector_type(4))) float f32x4;

__device__ __forceinline__ float sigf(float x) { return 1.0f / (1.0f + __expf(-x)); }
__device__ __forceinline__ float tanhfast(float x) { return 2.0f / (1.0f + __expf(-2.0f * x)) - 1.0f; }
__device__ __forceinline__ unsigned short f2bf(float f) {
    union { float f; unsigned u; } v; v.f = f;
    unsigned r = v.u + 0x7FFFu + ((v.u >> 16) & 1u);   // RNE
    return (unsigned short)(r >> 16);
}

// ---------------------------------------------------------------------------
// One LSTM layer scan over all 512 steps. One block = 16 batch rows (M=16
// fully used by mfma_f32_16x16x32_bf16), 1024 threads = 16 waves.
// Wave w owns gates [w*32, w*32+32) (2 N-tiles); weights bf16 stationary in
// VGPRs (64 regs max). A = [x_t | h_{t-1}] rows 0..15 from LDS (padded, no
// bank conflicts). Epilogue stores RAW fp32 gates; activations + state update
// run 1024-wide (wave w = row w, lanes = units l, l+64). Producer (L1)
// streams h to global bf16 + sets per-CH-step flags; consumer (L2) spins.
// ---------------------------------------------------------------------------
template<int XW, bool IS_L1>
__device__ __forceinline__ void layer_scan(
    const void* __restrict__ xin,
    const float* __restrict__ w_ih, const float* __restrict__ w_hh,
    const float* __restrict__ b_ih, const float* __restrict__ b_hh,
    unsigned short* __restrict__ out1, int* __restrict__ flags,
    float* __restrict__ h2s,
    unsigned short* xwin, unsigned short* hb, float* abuf, int blk)
{
    const int tid = threadIdx.x;
    const int w   = tid >> 6;      // wave = gate-tile owner AND state row
    const int l   = tid & 63;
    const int lm  = l & 15;        // A row m / B,C col n
    const int kb  = l >> 4;        // k-subblock
    const int gbase = w * 32;
    const int r0  = blk * 16;
    constexpr int KT  = (XW + HH) / 32;
    constexpr int XWp = XW + 8;

    // --- stationary B fragments (bf16) + bias ---
    short8 bf0[KT], bf1[KT];
    float bv0, bv1;
    {
        const int g0 = gbase + lm, g1 = gbase + 16 + lm;
        bv0 = b_ih[g0] + b_hh[g0];
        bv1 = b_ih[g1] + b_hh[g1];
        #pragma unroll
        for (int kt = 0; kt < KT; kt++) {
            const int k0 = kt * 32 + kb * 8;
            const float* s0 = (k0 < XW) ? (w_ih + (size_t)g0 * XW + k0)
                                        : (w_hh + (size_t)g0 * HH + (k0 - XW));
            const float* s1 = (k0 < XW) ? (w_ih + (size_t)g1 * XW + k0)
                                        : (w_hh + (size_t)g1 * HH + (k0 - XW));
            short8 a, b;
            #pragma unroll
            for (int j = 0; j < 8; j++) { a[j] = (short)f2bf(s0[j]); b[j] = (short)f2bf(s1[j]); }
            bf0[kt] = a; bf1[kt] = b;
        }
    }

    // --- zero h buffer (incl. pad) ---
    for (int i = tid; i < 16 * HBP; i += 1024) hb[i] = 0;
    float c0 = 0.0f, c1 = 0.0f, h0v = 0.0f, h1v = 0.0f;
    __syncthreads();

    for (int tl = 0; tl < TT; tl++) {
        // ---- stage input window every WT steps ----
        if ((tl & (WT - 1)) == 0) {
            if (!IS_L1 && (tl & (CH - 1)) == 0) {
                if (tid == 0) {
                    while (__hip_atomic_load(&flags[blk * (TT / CH) + (tl >> 4)],
                                             __ATOMIC_ACQUIRE, __HIP_MEMORY_SCOPE_AGENT) == 0) {
                        __builtin_amdgcn_s_sleep(8);
                    }
                }
                __syncthreads();
                // every thread acquires (invalidates its caches for the data reads)
                (void)__hip_atomic_load(&flags[blk * (TT / CH) + (tl >> 4)],
                                        __ATOMIC_ACQUIRE, __HIP_MEMORY_SCOPE_AGENT);
            }
            if (IS_L1) {
                const float* xf = (const float*)xin;
                const int f = tid * 4;
                const int row = f >> 8, rem = f & 255, tt = rem >> 6, k = rem & 63;
                const float4 v = *(const float4*)(xf + ((size_t)(r0 + row) * TT + (tl + tt)) * FF + k);
                uint2 p;
                p.x = (unsigned)f2bf(v.x) | ((unsigned)f2bf(v.y) << 16);
                p.y = (unsigned)f2bf(v.z) | ((unsigned)f2bf(v.w) << 16);
                *(uint2*)&xwin[(tt * 16 + row) * XWP1 + k] = p;
            } else {
                const unsigned short* xs = (const unsigned short*)xin;
                const int f = tid * 8;
                const int row = f >> 9, rem = f & 511, tt = rem >> 7, k = rem & 127;
                const uint4 v = *(const uint4*)(xs + ((size_t)(r0 + row) * TT + (tl + tt)) * HH + k);
                *(uint4*)&xwin[(tt * 16 + row) * XWP2 + k] = v;
            }
            __syncthreads();
        }
        const int tloc = tl & (WT - 1);

        // ---- MFMA: raw gates = bias + [x|h] @ Wcat^T, all 16 rows used ----
        f32x4 acc0 = {bv0, bv0, bv0, bv0};
        f32x4 acc1 = {bv1, bv1, bv1, bv1};
        {
            const unsigned short* aX = &xwin[(tloc * 16 + lm) * XWp + kb * 8];
            const unsigned short* aH = &hb[lm * HBP + kb * 8];
            #pragma unroll
            for (int kt = 0; kt < KT; kt++) {
                const unsigned short* ap = (kt * 32 < XW) ? (aX + kt * 32)
                                                          : (aH + (kt * 32 - XW));
                const short8 a = *(const short8*)ap;
                acc0 = __builtin_amdgcn_mfma_f32_16x16x32_bf16(a, bf0[kt], acc0, 0, 0, 0);
                acc1 = __builtin_amdgcn_mfma_f32_16x16x32_bf16(a, bf1[kt], acc1, 0, 0, 0);
            }
        }
        // epilogue: raw fp32 gates to abuf (row = batch row, col = gate)
        #pragma unroll
        for (int r = 0; r < 4; r++) {
            const int row = kb * 4 + r;
            abuf[row * ABP + gbase + lm]      = acc0[r];
            abuf[row * ABP + gbase + 16 + lm] = acc1[r];
        }
        __syncthreads();   // gates ready

        // ---- state update: wave w = row w; lanes handle units l and l+64 ----
        {
            const float* ab = &abuf[w * ABP];
            const float i0 = sigf(ab[l]);
            const float f0 = sigf(ab[HH + l]);
            const float g0 = tanhfast(ab[2 * HH + l]);
            const float o0 = sigf(ab[3 * HH + l]);
            c0 = f0 * c0 + i0 * g0;
            h0v = o0 * tanhfast(c0);
            const float i1 = sigf(ab[64 + l]);
            const float f1 = sigf(ab[HH + 64 + l]);
            const float g1 = tanhfast(ab[2 * HH + 64 + l]);
            const float o1 = sigf(ab[3 * HH + 64 + l]);
            c1 = f1 * c1 + i1 * g1;
            h1v = o1 * tanhfast(c1);
            const unsigned short hb0 = f2bf(h0v), hb1 = f2bf(h1v);
            hb[w * HBP + l]      = hb0;
            hb[w * HBP + 64 + l] = hb1;
            if (IS_L1) {
                unsigned short* op = out1 + ((size_t)(r0 + w) * TT + tl) * HH;
                op[l]      = hb0;
                op[64 + l] = hb1;
            }
        }

        if (IS_L1 && (tl & (CH - 1)) == (CH - 1)) {
            __threadfence();          // drain + make this thread's stores device-visible
            __syncthreads();          // all threads' fences done; doubles as barrier #2
            if (tid == 0)
                __hip_atomic_fetch_add(&flags[blk * (TT / CH) + (tl >> 4)], 1,
                                       __ATOMIC_RELEASE, __HIP_MEMORY_SCOPE_AGENT);
        } else {
            __syncthreads();          // barrier #2: hb/abuf safe for next step
        }
    }

    if (!IS_L1) {
        h2s[(size_t)(r0 + w) * HH + l]      = h0v;
        h2s[(size_t)(r0 + w) * HH + 64 + l] = h1v;
    }
}

__global__ __launch_bounds__(1024, 1) void lstm_fused(
    const float* __restrict__ x,
    const float* __restrict__ w1_ih, const float* __restrict__ w1_hh,
    const float* __restrict__ b1_ih, const float* __restrict__ b1_hh,
    const float* __restrict__ w2_ih, const float* __restrict__ w2_hh,
    const float* __restrict__ b2_ih, const float* __restrict__ b2_hh,
    unsigned short* __restrict__ out1, int* __restrict__ flags,
    float* __restrict__ h2s)
{
    __shared__ __align__(16) unsigned short xwin[WT * 16 * XWP2];  // 17408 B (max of L1/L2)
    __shared__ __align__(16) unsigned short hb[16 * HBP];          //  4352 B
    __shared__ __align__(16) float abuf[16 * ABP];                 // 33024 B
    const int bid = blockIdx.x;
    if (bid < 32)
        layer_scan<FF, true >(x, w1_ih, w1_hh, b1_ih, b1_hh, out1, flags, nullptr,
                              xwin, hb, abuf, bid);
    else
        layer_scan<HH, false>(out1, w2_ih, w2_hh, b2_ih, b2_hh, nullptr, flags, h2s,
                              xwin, hb, abuf, bid - 32);
}

// ---------------------------------------------------------------------------
// logits = h2_last @ w_fc^T + b_fc; sigmoid.
// ---------------------------------------------------------------------------
__global__ void final_kernel(const float* __restrict__ h2s,
                             const float* __restrict__ w_fc,
                             const float* __restrict__ b_fc,
                             float* __restrict__ out)
{
    const int idx = blockIdx.x * blockDim.x + threadIdx.x;
    if (idx >= BB * NCLS) return;
    const int b = idx / NCLS, cls = idx % NCLS;
    const float* hp = h2s + (size_t)b * HH;
    const float* wp = w_fc + (size_t)cls * HH;
    float acc = b_fc[cls];
    #pragma unroll 8
    for (int k = 0; k < HH; k++) acc += hp[k] * wp[k];
    out[idx] = sigf(acc);
}

extern "C" void kernel_launch(void* const* d_in, const int* in_sizes, int n_in,
                              void* d_out, int out_size, void* d_ws, size_t ws_size,
                              hipStream_t stream)
{
    const float* x     = (const float*)d_in[0];
    const float* w1_ih = (const float*)d_in[1];
    const float* w1_hh = (const float*)d_in[2];
    const float* b1_ih = (const float*)d_in[3];
    const float* b1_hh = (const float*)d_in[4];
    const float* w2_ih = (const float*)d_in[5];
    const float* w2_hh = (const float*)d_in[6];
    const float* b2_ih = (const float*)d_in[7];
    const float* b2_hh = (const float*)d_in[8];
    const float* w_fc  = (const float*)d_in[9];
    const float* b_fc  = (const float*)d_in[10];
    float* out = (float*)d_out;

    // workspace: [h2s fp32 256KB | flags 4KB | out1 bf16 64MB]
    char* ws = (char*)d_ws;
    float* h2s = (float*)ws;                 ws += (size_t)BB * HH * sizeof(float);
    int* flags = (int*)ws;                   ws += 4096;
    unsigned short* out1 = (unsigned short*)ws;

    hipMemsetAsync(flags, 0, 32 * (TT / CH) * sizeof(int), stream);
    lstm_fused<<<64, 1024, 0, stream>>>(x, w1_ih, w1_hh, b1_ih, b1_hh,
                                        w2_ih, w2_hh, b2_ih, b2_hh,
                                        out1, flags, h2s);
    final_kernel<<<(BB * NCLS + 255) / 256, 256, 0, stream>>>(h2s, w_fc, b_fc, out);
}